// Round 1
// baseline (438.806 us; speedup 1.0000x reference)
//
#include <hip/hip_runtime.h>
#include <hip/hip_bf16.h>

// Problem constants (fixed by reference)
#define BB 4
#define NN 4096
#define DF 128          // D_FEAT == UNITS == 128
#define ROWS (BB*NN)    // 16384
#define CAP 128         // per-receiver edge bucket capacity (mean deg 41, sd 6.4)

// ---------------------------------------------------------------------------
// Kernel 1: scan adj (fp32 0/1, 268 MB) -> per-receiver edge lists.
// deg = sum over s of adj[b][s][r]  (column sums). One thread per float4.
// Element index e: b = e>>24, s = (e>>12)&4095, r = e&4095.
// ---------------------------------------------------------------------------
__global__ __launch_bounds__(256) void scan_adj(const float* __restrict__ adj,
                                                int* __restrict__ cnt,
                                                int* __restrict__ bucket) {
    int tid = blockIdx.x * 256 + threadIdx.x;          // < 16777216
    float4 v = ((const float4*)adj)[tid];
    int e = tid << 2;
    int b = e >> 24;
    int s = (e >> 12) & 4095;
    int rgbase = (b << 12) | (e & 4095);               // b*4096 + r
    float vals[4] = {v.x, v.y, v.z, v.w};
#pragma unroll
    for (int k = 0; k < 4; ++k) {
        if (vals[k] != 0.0f) {
            int rg = rgbase + k;
            int slot = atomicAdd(&cnt[rg], 1);
            if (slot < CAP) bucket[rg * CAP + slot] = s;
        }
    }
}

// ---------------------------------------------------------------------------
// Kernel 2: fold weights.  Wcat (128 x 384):
//   cols   0:128 = Wu_top[k][j]            = W_upd[k][j]
//   cols 128:256 = (Wr @ Wu_bot)[k][j]     (Wr = W_msg[128:], Wu_bot = W_upd[128:])
//   cols 256:384 = (Ws @ Wu_bot)[k][j]     (Ws = W_msg[:128])
// ---------------------------------------------------------------------------
__global__ __launch_bounds__(128) void fold_weights(const float* __restrict__ Wmsg,
                                                    const float* __restrict__ Wupd,
                                                    float* __restrict__ Wcat) {
    __shared__ float ldsS[128], ldsR[128];
    int k = blockIdx.x, t = threadIdx.x;
    ldsS[t] = Wmsg[k * 128 + t];            // Ws[k][t]
    ldsR[t] = Wmsg[(128 + k) * 128 + t];    // Wr[k][t]
    __syncthreads();
    float a1 = 0.f, a2 = 0.f;
#pragma unroll 8
    for (int m = 0; m < 128; ++m) {
        float wu = Wupd[(128 + m) * 128 + t];   // Wu_bot[m][t], coalesced
        a1 += ldsS[m] * wu;
        a2 += ldsR[m] * wu;
    }
    Wcat[k * 384 + t]       = Wupd[k * 128 + t];
    Wcat[k * 384 + 128 + t] = a2;
    Wcat[k * 384 + 256 + t] = a1;
}

// ---------------------------------------------------------------------------
// Kernel 3: Y = x @ Wcat   (16384x128 @ 128x384), fp32 register-tiled.
// BM=64, BK=64 (2 chunks), BN=128; 256 threads = 16x16 groups, 4x8 micro-tile.
// ---------------------------------------------------------------------------
#define BM 64
#define BK 64
#define BN 128
__global__ __launch_bounds__(256) void gemm_x_wcat(const float* __restrict__ X,
                                                   const float* __restrict__ Wcat,
                                                   float* __restrict__ Y) {
    __shared__ float As[BM][68];   // stride 68 floats = 272 B (16B-aligned, 2-way-bank-free)
    __shared__ float Bs[BK][BN];
    int t  = threadIdx.x;
    int m0 = blockIdx.x * BM;
    int n0 = blockIdx.y * BN;
    int cn = t & 15;               // 8 cols each
    int cm = t >> 4;               // 4 rows each

    float acc[4][8];
#pragma unroll
    for (int i = 0; i < 4; ++i)
#pragma unroll
        for (int j = 0; j < 8; ++j) acc[i][j] = 0.f;

    for (int c = 0; c < 2; ++c) {
        // stage A chunk: 64 rows x 64 k = 1024 float4, 4/thread
#pragma unroll
        for (int i = 0; i < 4; ++i) {
            int f = t + 256 * i;
            int m = f >> 4, k4 = f & 15;
            float4 v = *(const float4*)(X + (size_t)(m0 + m) * 128 + c * 64 + k4 * 4);
            *(float4*)(&As[m][k4 * 4]) = v;
        }
        // stage B chunk: 64 k x 128 n = 2048 float4, 8/thread
#pragma unroll
        for (int i = 0; i < 8; ++i) {
            int f = t + 256 * i;
            int k = f >> 5, n4 = f & 31;
            float4 v = *(const float4*)(Wcat + (size_t)(c * 64 + k) * 384 + n0 + n4 * 4);
            *(float4*)(&Bs[k][n4 * 4]) = v;
        }
        __syncthreads();
#pragma unroll 8
        for (int kk = 0; kk < BK; ++kk) {
            float a0 = As[cm * 4 + 0][kk];
            float a1 = As[cm * 4 + 1][kk];
            float a2 = As[cm * 4 + 2][kk];
            float a3 = As[cm * 4 + 3][kk];
            float4 b0 = *(float4*)(&Bs[kk][cn * 8]);
            float4 b1 = *(float4*)(&Bs[kk][cn * 8 + 4]);
            float bv[8] = {b0.x, b0.y, b0.z, b0.w, b1.x, b1.y, b1.z, b1.w};
            float av[4] = {a0, a1, a2, a3};
#pragma unroll
            for (int i = 0; i < 4; ++i)
#pragma unroll
                for (int j = 0; j < 8; ++j) acc[i][j] += av[i] * bv[j];
        }
        __syncthreads();
    }
#pragma unroll
    for (int i = 0; i < 4; ++i) {
        int row = m0 + cm * 4 + i;
        float* p = Y + (size_t)row * 384 + n0 + cn * 8;
        float4 o0 = {acc[i][0], acc[i][1], acc[i][2], acc[i][3]};
        float4 o1 = {acc[i][4], acc[i][5], acc[i][6], acc[i][7]};
        *(float4*)(p)     = o0;
        *(float4*)(p + 4) = o1;
    }
}

// ---------------------------------------------------------------------------
// Kernel 4: gather + epilogue.
// out[rg][j] = t1 + (cnt>0 ? d2 + (1/cnt)*sum_{s in bucket} y[s][j] : 0)
// Y row layout: [0:128]=t1, [128:256]=d2, [256:384]=y. Block = 2 receivers.
// ---------------------------------------------------------------------------
__global__ __launch_bounds__(256) void gather_out(const float* __restrict__ Y,
                                                  const int* __restrict__ cnt,
                                                  const int* __restrict__ bucket,
                                                  float* __restrict__ out) {
    __shared__ int lds_s[2][CAP];
    int t = threadIdx.x;
    int sub = t >> 7, j = t & 127;
    int rg = blockIdx.x * 2 + sub;
    int c = cnt[rg];
    if (c > CAP) c = CAP;
    if (j < c) lds_s[sub][j] = bucket[rg * CAP + j];
    __syncthreads();
    const float* Yrow = Y + (size_t)rg * 384;
    float t1 = Yrow[j];
    float res;
    if (c > 0) {
        int b = rg >> 12;
        const float* ybase = Y + ((size_t)b << 12) * 384 + 256 + j;
        float acc = 0.f;
        for (int e = 0; e < c; ++e) {
            int s = lds_s[sub][e];
            acc += ybase[(size_t)s * 384];
        }
        res = t1 + Yrow[128 + j] + acc * (1.0f / (float)c);
    } else {
        res = t1;
    }
    out[(size_t)rg * 128 + j] = res;
}

// ---------------------------------------------------------------------------
extern "C" void kernel_launch(void* const* d_in, const int* in_sizes, int n_in,
                              void* d_out, int out_size, void* d_ws, size_t ws_size,
                              hipStream_t stream) {
    const float* x    = (const float*)d_in[0];   // 16384 x 128
    const float* adj  = (const float*)d_in[1];   // 4 x 4096 x 4096
    const float* Wmsg = (const float*)d_in[2];   // 256 x 128
    const float* Wupd = (const float*)d_in[3];   // 256 x 128
    float* out = (float*)d_out;                  // 16384 x 128

    // workspace layout (bytes)
    char* ws = (char*)d_ws;
    float* Wcat  = (float*)(ws);                          // 128*384*4   = 196608
    float* Y     = (float*)(ws + 196608);                 // 16384*384*4 = 25165824
    int*   cntb  = (int*)  (ws + 196608 + 25165824);      // 16384*4     = 65536
    int*   bucket= (int*)  (ws + 196608 + 25165824 + 65536); // 16384*128*4 = 8388608
    // total ~33.8 MB

    hipMemsetAsync(cntb, 0, ROWS * sizeof(int), stream);

    scan_adj<<<(BB * NN * NN) / 4 / 256, 256, 0, stream>>>(adj, cntb, bucket);
    fold_weights<<<128, 128, 0, stream>>>(Wmsg, Wupd, Wcat);
    gemm_x_wcat<<<dim3(ROWS / BM, 3), 256, 0, stream>>>(x, Wcat, Y);
    gather_out<<<ROWS / 2, 256, 0, stream>>>(Y, cntb, bucket, out);
}